// Round 2
// baseline (710.531 us; speedup 1.0000x reference)
//
#include <hip/hip_runtime.h>
#include <cstdint>
#include <cstddef>

#define N_NODES 50000
#define N_EDGES 800000
#define N_ETOT  850000   // E + N self-loops
#define DIM     128
#define NHEAD   8
#define NGRAPH  100
#define NLAT    64
#define NSCAN   49       // ceil(50000/1024)
#define NEG_SLOPE 0.2f
#define BN_EPS  1e-5f

typedef unsigned int u32;

// ---------------- CSR build ----------------

__global__ void k_degree(const int* __restrict__ ei, int* __restrict__ deg){
    int e = blockIdx.x * blockDim.x + threadIdx.x;
    if (e < N_ETOT) {
        int d = (e < N_EDGES) ? ei[N_EDGES + e] : (e - N_EDGES);
        atomicAdd(&deg[d], 1);
    }
}

__global__ void k_bsum(const int* __restrict__ deg, int* __restrict__ bsum){
    __shared__ int s[256];
    int b = blockIdx.x, tid = threadIdx.x;
    int base = b * 1024 + tid * 4;
    int sum = 0;
    #pragma unroll
    for (int j = 0; j < 4; j++) { int n = base + j; if (n < N_NODES) sum += deg[n]; }
    s[tid] = sum; __syncthreads();
    for (int off = 128; off > 0; off >>= 1) {
        if (tid < off) s[tid] += s[tid + off];
        __syncthreads();
    }
    if (tid == 0) bsum[b] = s[0];
}

__global__ void k_scan_bsum(const int* __restrict__ bsum, int* __restrict__ boff,
                            int* __restrict__ rowptr){
    if (threadIdx.x == 0) {
        int acc = 0;
        for (int i = 0; i < NSCAN; i++) { boff[i] = acc; acc += bsum[i]; }
        rowptr[N_NODES] = acc;   // == N_ETOT
    }
}

__global__ void k_scan_local(const int* __restrict__ deg, const int* __restrict__ boff,
                             int* __restrict__ rowptr){
    __shared__ int s[256];
    int b = blockIdx.x, tid = threadIdx.x;
    int base = b * 1024 + tid * 4;
    int v[4];
    int sum = 0;
    #pragma unroll
    for (int j = 0; j < 4; j++) {
        int n = base + j;
        v[j] = (n < N_NODES) ? deg[n] : 0;
        sum += v[j];
    }
    s[tid] = sum; __syncthreads();
    for (int off = 1; off < 256; off <<= 1) {
        int t = (tid >= off) ? s[tid - off] : 0;
        __syncthreads();
        s[tid] += t;
        __syncthreads();
    }
    int ex = (tid ? s[tid - 1] : 0) + boff[b];
    #pragma unroll
    for (int j = 0; j < 4; j++) {
        int n = base + j;
        if (n < N_NODES) rowptr[n] = ex;
        ex += v[j];
    }
}

__global__ void k_initcur(const int* __restrict__ rowptr, int* __restrict__ cur){
    int n = blockIdx.x * blockDim.x + threadIdx.x;
    if (n < N_NODES) cur[n] = rowptr[n];
}

__global__ void k_scatter(const int* __restrict__ ei, int* __restrict__ cur,
                          int* __restrict__ csr){
    int e = blockIdx.x * blockDim.x + threadIdx.x;
    if (e < N_ETOT) {
        int s, d;
        if (e < N_EDGES) { s = ei[e]; d = ei[N_EDGES + e]; }
        else             { s = e - N_EDGES; d = s; }
        int pos = atomicAdd(&cur[d], 1);
        csr[pos] = s;
    }
}

// ---------------- per-layer: x @ W -> hp (fp32) ----------------
// block: 256 thr, 64 rows/block. LDS: xs 32KB fp32.
// thread (cq=tid&31, rg=tid>>5): cols 4cq..4cq+3, rows rg*8..rg*8+7.
// W (64KB) read straight from global; every block touches the same 64KB -> L2 hits.

__launch_bounds__(256)
__global__ void k_gemm(const float* __restrict__ x, const float* __restrict__ W,
                       float* __restrict__ hp){
    __shared__ float xs[64 * 128];
    const int tid = threadIdx.x;
    const int r0  = blockIdx.x * 64;

    for (int c = tid; c < 2048; c += 256) {          // 64 rows x 32 float4
        int row = r0 + (c >> 5);
        float4 v = make_float4(0.f, 0.f, 0.f, 0.f);
        if (row < N_NODES) v = *(const float4*)(x + (size_t)row * 128 + (c & 31) * 4);
        *(float4*)(xs + c * 4) = v;
    }
    __syncthreads();

    const int cq = tid & 31;
    const int rg = tid >> 5;
    float acc[8][4];
    #pragma unroll
    for (int r = 0; r < 8; r++)
        #pragma unroll
        for (int c = 0; c < 4; c++) acc[r][c] = 0.f;

    for (int k = 0; k < 128; k += 4) {
        float4 w0 = *(const float4*)(W + (k + 0) * 128 + 4 * cq);
        float4 w1 = *(const float4*)(W + (k + 1) * 128 + 4 * cq);
        float4 w2 = *(const float4*)(W + (k + 2) * 128 + 4 * cq);
        float4 w3 = *(const float4*)(W + (k + 3) * 128 + 4 * cq);
        #pragma unroll
        for (int rr = 0; rr < 8; rr++) {
            float4 xv = *(const float4*)(xs + (rg * 8 + rr) * 128 + k);
            acc[rr][0] = fmaf(xv.x, w0.x, acc[rr][0]);
            acc[rr][1] = fmaf(xv.x, w0.y, acc[rr][1]);
            acc[rr][2] = fmaf(xv.x, w0.z, acc[rr][2]);
            acc[rr][3] = fmaf(xv.x, w0.w, acc[rr][3]);
            acc[rr][0] = fmaf(xv.y, w1.x, acc[rr][0]);
            acc[rr][1] = fmaf(xv.y, w1.y, acc[rr][1]);
            acc[rr][2] = fmaf(xv.y, w1.z, acc[rr][2]);
            acc[rr][3] = fmaf(xv.y, w1.w, acc[rr][3]);
            acc[rr][0] = fmaf(xv.z, w2.x, acc[rr][0]);
            acc[rr][1] = fmaf(xv.z, w2.y, acc[rr][1]);
            acc[rr][2] = fmaf(xv.z, w2.z, acc[rr][2]);
            acc[rr][3] = fmaf(xv.z, w2.w, acc[rr][3]);
            acc[rr][0] = fmaf(xv.w, w3.x, acc[rr][0]);
            acc[rr][1] = fmaf(xv.w, w3.y, acc[rr][1]);
            acc[rr][2] = fmaf(xv.w, w3.z, acc[rr][2]);
            acc[rr][3] = fmaf(xv.w, w3.w, acc[rr][3]);
        }
    }

    #pragma unroll
    for (int rr = 0; rr < 8; rr++) {
        int row = r0 + rg * 8 + rr;
        if (row < N_NODES)
            *(float4*)(hp + (size_t)row * 128 + 4 * cq) =
                make_float4(acc[rr][0], acc[rr][1], acc[rr][2], acc[rr][3]);
    }
}

// ---------------- per-layer: attention logit dot products ----------------

__global__ void k_alpha(const float* __restrict__ hp, const float* __restrict__ asrc,
                        const float* __restrict__ adst,
                        float* __restrict__ as_, float* __restrict__ ad_){
    int id = blockIdx.x * blockDim.x + threadIdx.x;
    if (id >= N_NODES * NHEAD) return;
    int h = id & 7;
    const float4* hpp = (const float4*)hp + (size_t)id * 4;   // 16 floats
    const float4* av  = (const float4*)asrc + h * 4;
    const float4* bv  = (const float4*)adst + h * 4;
    float s0 = 0.f, s1 = 0.f;
    #pragma unroll
    for (int j = 0; j < 4; j++) {
        float4 v = hpp[j];
        float4 a = av[j], b = bv[j];
        s0 = fmaf(v.x, a.x, s0); s0 = fmaf(v.y, a.y, s0);
        s0 = fmaf(v.z, a.z, s0); s0 = fmaf(v.w, a.w, s0);
        s1 = fmaf(v.x, b.x, s1); s1 = fmaf(v.y, b.y, s1);
        s1 = fmaf(v.z, b.z, s1); s1 = fmaf(v.w, b.w, s1);
    }
    as_[id] = s0;
    ad_[id] = s1;
}

// ---------------- per-layer: segment softmax + aggregate + bias + ELU ----------
// one wave per destination node; 4 waves / 256-thr block.

__launch_bounds__(256)
__global__ void k_agg(const int* __restrict__ rowptr, const int* __restrict__ csr,
                      const float* __restrict__ as_, const float* __restrict__ ad_,
                      const float* __restrict__ hp, const float* __restrict__ bias,
                      float* __restrict__ xout){
    const int lane = threadIdx.x & 63;
    const int wid  = threadIdx.x >> 6;
    const int n    = blockIdx.x * 4 + wid;
    if (n >= N_NODES) return;
    const int beg = rowptr[n], end = rowptr[n + 1];
    const int items = (end - beg) * 8;
    const int hme = lane & 7;
    const float adn = ad_[(size_t)n * 8 + hme];

    // phase 1: per-head max of leaky_relu(as[src]+ad[n])
    float m = -1e30f;
    for (int j = lane; j < items; j += 64) {
        int s = csr[beg + (j >> 3)];
        float v = as_[(size_t)s * 8 + hme] + adn;
        v = v > 0.f ? v : NEG_SLOPE * v;
        m = fmaxf(m, v);
    }
    m = fmaxf(m, __shfl_xor(m, 8));
    m = fmaxf(m, __shfl_xor(m, 16));
    m = fmaxf(m, __shfl_xor(m, 32));

    // phase 2: per-head sum of exp(logit - m)
    float den = 0.f;
    for (int j = lane; j < items; j += 64) {
        int s = csr[beg + (j >> 3)];
        float v = as_[(size_t)s * 8 + hme] + adn;
        v = v > 0.f ? v : NEG_SLOPE * v;
        den += __expf(v - m);
    }
    den += __shfl_xor(den, 8);
    den += __shfl_xor(den, 16);
    den += __shfl_xor(den, 32);

    // phase 3: weighted aggregate. lane owns cols lane (head h1) and lane+64 (head h2).
    const int h1 = lane >> 4, h2 = h1 + 4;
    const float m1 = __shfl(m, h1),  m2 = __shfl(m, h2);
    const float i1 = 1.f / (__shfl(den, h1) + 1e-16f);
    const float i2 = 1.f / (__shfl(den, h2) + 1e-16f);
    const float an1 = __shfl(adn, h1), an2 = __shfl(adn, h2);
    float acc1 = 0.f, acc2 = 0.f;
    for (int e = beg; e < end; e++) {
        int s = csr[e];
        float v1 = as_[(size_t)s * 8 + h1] + an1; v1 = v1 > 0.f ? v1 : NEG_SLOPE * v1;
        float v2 = as_[(size_t)s * 8 + h2] + an2; v2 = v2 > 0.f ? v2 : NEG_SLOPE * v2;
        float a1 = __expf(v1 - m1) * i1;
        float a2 = __expf(v2 - m2) * i2;
        acc1 = fmaf(a1, hp[(size_t)s * 128 + lane],      acc1);
        acc2 = fmaf(a2, hp[(size_t)s * 128 + 64 + lane], acc2);
    }

    float o1 = acc1 + bias[lane];
    float o2 = acc2 + bias[64 + lane];
    o1 = o1 > 0.f ? o1 : (__expf(o1) - 1.f);   // ELU
    o2 = o2 > 0.f ? o2 : (__expf(o2) - 1.f);
    xout[(size_t)n * 128 + lane]      = o1;
    xout[(size_t)n * 128 + 64 + lane] = o2;
}

// ---------------- pooling / BN / FC ----------------

__global__ void k_pool(const float* __restrict__ x, const int* __restrict__ batch,
                       float* __restrict__ pooled){
    int tid = threadIdx.x;             // 128 = feature
    int n0 = blockIdx.x * 128;
    int nend = min(n0 + 128, N_NODES);
    float acc = 0.f;
    int cur = batch[n0];
    for (int n = n0; n < nend; n++) {
        int g = batch[n];
        if (g != cur) {
            atomicAdd(&pooled[cur * 128 + tid], acc);
            acc = 0.f; cur = g;
        }
        acc += x[(size_t)n * 128 + tid];
    }
    atomicAdd(&pooled[cur * 128 + tid], acc);
}

__global__ void k_bn(const float* __restrict__ pooled, const float* __restrict__ gamma,
                     const float* __restrict__ beta, float* __restrict__ normed){
    int f = threadIdx.x;   // 128
    float mu = 0.f;
    for (int g = 0; g < NGRAPH; g++) mu += pooled[g * 128 + f];
    mu *= (1.f / NGRAPH);
    float var = 0.f;
    for (int g = 0; g < NGRAPH; g++) { float d = pooled[g * 128 + f] - mu; var += d * d; }
    var *= (1.f / NGRAPH);
    float rs = rsqrtf(var + BN_EPS);
    float ga = gamma[f], be = beta[f];
    for (int g = 0; g < NGRAPH; g++)
        normed[g * 128 + f] = (pooled[g * 128 + f] - mu) * rs * ga + be;
}

__global__ void k_fc(const float* __restrict__ normed, const float* __restrict__ fw,
                     const float* __restrict__ fb, float* __restrict__ out){
    int g = blockIdx.x, j = threadIdx.x;   // 100 x 64
    float acc = fb[j];
    const float* wr = fw + j * 128;
    const float* nr = normed + g * 128;
    #pragma unroll
    for (int k = 0; k < 128; k++)
        acc = fmaf(nr[k], wr[k], acc);
    out[g * 64 + j] = acc;
}

// ---------------- launch ----------------

extern "C" void kernel_launch(void* const* d_in, const int* in_sizes, int n_in,
                              void* d_out, int out_size, void* d_ws, size_t ws_size,
                              hipStream_t stream) {
    const float* x0    = (const float*)d_in[0];
    const int*   ei    = (const int*)d_in[1];
    const int*   batch = (const int*)d_in[2];
    const float* Wp    = (const float*)d_in[3];
    const float* asrc  = (const float*)d_in[4];
    const float* adst  = (const float*)d_in[5];
    const float* bias  = (const float*)d_in[6];
    const float* gamma = (const float*)d_in[7];
    const float* beta  = (const float*)d_in[8];
    const float* fw    = (const float*)d_in[9];
    const float* fb    = (const float*)d_in[10];
    float* out = (float*)d_out;

    char* w = (char*)d_ws;
    size_t off = 0;
    auto take = [&](size_t bytes) -> char* {
        char* p = w + off;
        off += (bytes + 255) & ~(size_t)255;
        return p;
    };
    int*   rowptr = (int*)take((N_NODES + 1) * 4);
    int*   cur    = (int*)take((size_t)N_NODES * 4);      // also the degree histogram
    int*   bsum   = (int*)take(64 * 4);
    int*   boff   = (int*)take(64 * 4);
    int*   csr    = (int*)take((size_t)N_ETOT * 4);
    float* hp     = (float*)take((size_t)N_NODES * 128 * 4);
    float* as_    = (float*)take((size_t)N_NODES * 8 * 4);
    float* ad_    = (float*)take((size_t)N_NODES * 8 * 4);
    float* xb1    = (float*)take((size_t)N_NODES * 128 * 4);
    float* xb2    = (float*)take((size_t)N_NODES * 128 * 4);
    float* pooled = (float*)take((size_t)NGRAPH * 128 * 4);
    float* normed = (float*)take((size_t)NGRAPH * 128 * 4);

    hipMemsetAsync(cur, 0, (size_t)N_NODES * 4, stream);
    hipMemsetAsync(pooled, 0, (size_t)NGRAPH * 128 * 4, stream);

    // CSR build (by destination)
    k_degree   <<<(N_ETOT + 255) / 256, 256, 0, stream>>>(ei, cur);
    k_bsum     <<<NSCAN, 256, 0, stream>>>(cur, bsum);
    k_scan_bsum<<<1, 64, 0, stream>>>(bsum, boff, rowptr);
    k_scan_local<<<NSCAN, 256, 0, stream>>>(cur, boff, rowptr);
    k_initcur  <<<(N_NODES + 255) / 256, 256, 0, stream>>>(rowptr, cur);
    k_scatter  <<<(N_ETOT + 255) / 256, 256, 0, stream>>>(ei, cur, csr);

    // 3 GAT layers
    const float* xc = x0;
    float* bufs[2] = { xb1, xb2 };
    for (int l = 0; l < 3; l++) {
        float* xn = bufs[l & 1];
        k_gemm <<<(N_NODES + 63) / 64, 256, 0, stream>>>(xc, Wp + (size_t)l * 128 * 128, hp);
        k_alpha<<<(N_NODES * NHEAD + 255) / 256, 256, 0, stream>>>(hp, asrc + l * 128, adst + l * 128, as_, ad_);
        k_agg  <<<(N_NODES + 3) / 4, 256, 0, stream>>>(rowptr, csr, as_, ad_, hp, bias + l * 128, xn);
        xc = xn;
    }

    // pool -> BN -> FC
    k_pool<<<(N_NODES + 127) / 128, 128, 0, stream>>>(xc, batch, pooled);
    k_bn  <<<1, 128, 0, stream>>>(pooled, gamma, beta, normed);
    k_fc  <<<NGRAPH, NLAT, 0, stream>>>(normed, fw, fb, out);
}